// Round 1
// 1099.847 us; speedup vs baseline: 1.1433x; 1.1433x over previous
//
#include <hip/hip_runtime.h>
#include <hip/hip_bf16.h>
#include <math.h>

// CircumpunctSSM: B=4, T=512, D=1024, S=16, dt_rank=64. All f32.
// Pipeline:
//   g1: siluxz[2048,2048] = silu(x @ W_in.T)        (x_in = cols 0..1023, silu(z) = cols 1024..2047)
//   g2: xp[2048,128]      = x_in @ W_xproj.T
//   g3: dt[2048,1024]     = softplus(xp[:, :64] @ W_dt.T + b_dt)
//   g4: xc[2048,32]       = x_in @ W_res.T
//   zero y; scan (64 blocks = B*S, 1024 thr = D): h recurrence + comp mean reduction + y atomics
//   g5: out = (y * silu(z)) @ W_out.T + b_out

enum { EPI_NONE=0, EPI_SILU=1, EPI_SPBIAS=2, EPI_BIAS=3 };

template<int EPI>
__device__ __forceinline__ float epi_apply(float v, float b) {
  if constexpr (EPI == EPI_SILU)        { return v / (1.0f + expf(-v)); }
  else if constexpr (EPI == EPI_SPBIAS) { float t = v + b; return fmaxf(t, 0.0f) + log1pf(expf(-fabsf(t))); }
  else if constexpr (EPI == EPI_BIAS)   { return v + b; }
  else return v;
}

// C[m,n] = EPI( sum_k Aeff[m,k]*W[n,k] (+bias[n]) ), Aeff = A (elementwise * A2 if HAS_A2)
// M is exact multiple of 64 (2048). N may not be multiple of 64 (guarded). K multiple of 16.
template<int EPI, bool HAS_A2>
__global__ __launch_bounds__(256) void gemm_wt(
    const float* __restrict__ A, int lda,
    const float* __restrict__ A2, int lda2,
    const float* __restrict__ W, int ldw,
    const float* __restrict__ bias,
    float* __restrict__ C, int ldc,
    int N, int K)
{
  constexpr int BM = 64, BN = 64, BK = 16, PAD = 4;
  __shared__ float As[BK][BM + PAD];
  __shared__ float Ws[BK][BN + PAD];
  const int m0 = blockIdx.x * BM;
  const int n0 = blockIdx.y * BN;
  const int tid = threadIdx.x;
  const int tx = tid & 15;        // n-direction (4 cols each)
  const int ty = tid >> 4;        // m-direction (4 rows each)
  const int lm = tid >> 2;        // 0..63 staging row
  const int lk = (tid & 3) << 2;  // 0,4,8,12 staging k (float4)

  float acc[4][4] = {{0.f,0.f,0.f,0.f},{0.f,0.f,0.f,0.f},{0.f,0.f,0.f,0.f},{0.f,0.f,0.f,0.f}};

  for (int k0 = 0; k0 < K; k0 += BK) {
    float4 av, wv;
    {
      const float* p = A + (size_t)(m0 + lm) * lda + k0 + lk;
      av = *(const float4*)p;
      if (HAS_A2) {
        const float4 a2 = *(const float4*)(A2 + (size_t)(m0 + lm) * lda2 + k0 + lk);
        av.x *= a2.x; av.y *= a2.y; av.z *= a2.z; av.w *= a2.w;
      }
    }
    {
      const int n = n0 + lm;
      if (n < N) wv = *(const float4*)(W + (size_t)n * ldw + k0 + lk);
      else       wv = make_float4(0.f, 0.f, 0.f, 0.f);
    }
    __syncthreads();   // protect previous iteration's LDS reads
    As[lk+0][lm] = av.x; As[lk+1][lm] = av.y; As[lk+2][lm] = av.z; As[lk+3][lm] = av.w;
    Ws[lk+0][lm] = wv.x; Ws[lk+1][lm] = wv.y; Ws[lk+2][lm] = wv.z; Ws[lk+3][lm] = wv.w;
    __syncthreads();
#pragma unroll
    for (int kk = 0; kk < BK; ++kk) {
      const float4 a = *(const float4*)&As[kk][ty << 2];
      const float4 w = *(const float4*)&Ws[kk][tx << 2];
      const float ar[4] = {a.x, a.y, a.z, a.w};
      const float wr[4] = {w.x, w.y, w.z, w.w};
#pragma unroll
      for (int i = 0; i < 4; ++i)
#pragma unroll
        for (int j = 0; j < 4; ++j)
          acc[i][j] = fmaf(ar[i], wr[j], acc[i][j]);
    }
  }

  const int ncol = n0 + (tx << 2);
  float bj[4] = {0.f, 0.f, 0.f, 0.f};
  if constexpr (EPI == EPI_SPBIAS || EPI == EPI_BIAS) {
    if (ncol < N) { const float4 bv = *(const float4*)(bias + ncol); bj[0]=bv.x; bj[1]=bv.y; bj[2]=bv.z; bj[3]=bv.w; }
  }
  if (ncol < N) {
#pragma unroll
    for (int i = 0; i < 4; ++i) {
      float vs[4];
#pragma unroll
      for (int j = 0; j < 4; ++j) vs[j] = epi_apply<EPI>(acc[i][j], bj[j]);
      *(float4*)(C + (size_t)(m0 + (ty << 2) + i) * ldc + ncol) = make_float4(vs[0], vs[1], vs[2], vs[3]);
    }
  }
}

__global__ void zero_kernel(float4* __restrict__ p, int n4) {
  const int i = blockIdx.x * blockDim.x + threadIdx.x;
  if (i < n4) p[i] = make_float4(0.f, 0.f, 0.f, 0.f);
}

// Scan: one block per (b,s); thread d owns h[b,d,s] (2 regs). Per step:
//   comp from released(h_prev, alpha) -> wave shuffle reduce -> LDS atomic (triple-buffered)
//   surfaced from d_prev (regs, replicated) -> h update -> y atomicAdd -> raw barrier -> d update.
//
// KEY CHANGE vs previous version: __syncthreads() forced the compiler to emit
// s_waitcnt vmcnt(0) before s_barrier every step, draining (a) the contended
// 16-way cross-XCD y atomicAdd and (b) any prefetched global loads — serializing
// ~1-2k cycles of memory latency into every one of the 512 steps. Only the LDS
// reduction (red[]) actually needs ordering at the barrier. We now use a raw
// s_barrier with an explicit lgkmcnt(0)-only drain, and software-prefetch the
// next step's inputs before the barrier so they stay in flight across it.
__global__ __launch_bounds__(1024) void scan_kernel(
    const float* __restrict__ xin,   // siluxz base, ld 2048 (cols 0..1023 = x_in)
    const float* __restrict__ xp,    // ld 128
    const float* __restrict__ dtb,   // ld 1024
    const float* __restrict__ xc,    // ld 32
    const float* __restrict__ A_log, // [16]
    float* __restrict__ y,           // ld 1024, pre-zeroed
    int T)
{
  const int b = blockIdx.x >> 4;
  const int s = blockIdx.x & 15;
  const int d = threadIdx.x;
  const int lane = threadIdx.x & 63;

  __shared__ float red[3][2];
  if (threadIdx.x == 0) {
    red[0][0] = 0.f; red[0][1] = 0.f;
    red[1][0] = 0.f; red[1][1] = 0.f;
    red[2][0] = 0.f; red[2][1] = 0.f;
  }

  const float a_s = expf(A_log[s]);                       // == s+1 (up to 1 ulp)
  const float phase = (float)(6.283185307179586 * (double)s / 16.0);
  float d_r = 0.01f * cosf(phase);
  float d_i = 0.01f * sinf(phase);
  float h_r = 0.f, h_i = 0.f;
  __syncthreads();   // once, before the loop: full sync is fine here

  // per-thread walking pointers (one row per step)
  const size_t rb = (size_t)b * T;
  const float* px  = xin + rb * 2048 + d;
  const float* pdt = dtb + rb * 1024 + d;
  const float* pB  = xp  + rb * 128 + 64 + 2 * s;
  const float* pC  = xp  + rb * 128 + 96 + 2 * s;
  const float* pxc = xc  + rb * 32 + 2 * s;
  float*       py  = y   + rb * 1024 + d;

  // preload t=0
  float  xv  = *px;
  float  dtv = *pdt;
  float2 Bv  = *(const float2*)pB;
  float2 Cv  = *(const float2*)pC;
  float2 xcv = *(const float2*)pxc;

  for (int t = 0; t < T; ++t) {
    const float alpha = __expf(-dtv * a_s);
    // released & comp (exact reference eps structure)
    const float om    = 1.0f - alpha;
    const float rel_r = h_r * om, rel_i = h_i * om;
    const float m2 = fmaf(rel_r, rel_r, fmaf(rel_i, rel_i, 1e-8f));
    const float cm = exp2f(log2f(m2) * (1.0f / 3.0f));    // mag^(2/3)
    const float rr = rel_r + 1e-10f;
    const float r2 = sqrtf(fmaf(rr, rr, fmaf(rel_i, rel_i, 1e-38f)));
    const float invr = 1.0f / r2;
    float c_r = cm * rr * invr;    c_r = fminf(fmaxf(c_r, -10.f), 10.f);
    float c_i = cm * rel_i * invr; c_i = fminf(fmaxf(c_i, -10.f), 10.f);

    // block reduction: wave shuffle -> LDS atomic into buffer t%3
    float w_r = c_r, w_i = c_i;
#pragma unroll
    for (int o = 32; o; o >>= 1) { w_r += __shfl_xor(w_r, o); w_i += __shfl_xor(w_i, o); }
    if (threadIdx.x == 0) { red[(t + 1) % 3][0] = 0.f; red[(t + 1) % 3][1] = 0.f; }
    if (lane == 0) { atomicAdd(&red[t % 3][0], w_r); atomicAdd(&red[t % 3][1], w_i); }

    // prefetch t+1 inputs NOW — they stay in flight across the raw barrier.
    // (At t==T-1 these read one row past each logical buffer; all such reads
    //  land inside the workspace allocation and the values are never used.)
    const float  xv_n  = px[2048];
    const float  dtv_n = pdt[1024];
    const float2 Bv_n  = *(const float2*)(pB + 128);
    const float2 Cv_n  = *(const float2*)(pC + 128);
    const float2 xcv_n = *(const float2*)(pxc + 32);

    // surfaced from d_prev (registers) + x_complex
    const float xr2 = xcv.x + 1e-10f;
    const float rx  = sqrtf(fmaf(xr2, xr2, fmaf(xcv.y, xcv.y, 1e-38f)));
    const float dr2 = d_r + 1e-10f;
    const float rdn = sqrtf(fmaf(dr2, dr2, fmaf(d_i, d_i, 1e-38f)));
    const float cosdp = fmaf(xr2, dr2, xcv.y * d_i) / (rx * rdn);
    const float Tg  = 0.5f * (1.0f + cosdp);              // cos^2((phix-phid)/2)
    const float dmag   = sqrtf(fmaf(d_r, d_r, fmaf(d_i, d_i, 1e-8f)));
    const float dscale = sqrtf(fminf(fmaxf(dmag, 1e-6f), 20.f));
    const float sfac = dscale * Tg / (dmag + 1e-8f);
    const float s_r = d_r * sfac, s_i = d_i * sfac;

    // h update
    const float bx_r = fmaf(Bv.x, xv, s_r) * dtv;
    const float bx_i = fmaf(Bv.y, xv, s_i) * dtv;
    h_r = fmaf(h_r, alpha, bx_r);
    h_i = fmaf(h_i, alpha, bx_i);

    // y contribution: Re(C * h), summed over s via fire-and-forget atomics
    // (never waited on — no vmcnt drain at the barrier below)
    atomicAdd(py, fmaf(Cv.x, h_r, -(Cv.y * h_i)));

    // raw barrier: drain LDS ops only; global loads/atomics stay in flight
    asm volatile("s_waitcnt lgkmcnt(0)" ::: "memory");
    __builtin_amdgcn_s_barrier();
    asm volatile("" ::: "memory");

    const float avg_r = red[t % 3][0] * (1.0f / 1024.0f);
    const float avg_i = red[t % 3][1] * (1.0f / 1024.0f);
    d_r = fmaf(0.01f, avg_r, d_r);
    d_i = fmaf(0.01f, avg_i, d_i);
    const float dmn = sqrtf(fmaf(d_r, d_r, fmaf(d_i, d_i, 1e-8f)));
    if (dmn > 20.f) { const float sc = 20.f / dmn; d_r *= sc; d_i *= sc; }

    // rotate prefetched state, advance pointers
    xv = xv_n; dtv = dtv_n; Bv = Bv_n; Cv = Cv_n; xcv = xcv_n;
    px += 2048; pdt += 1024; pB += 128; pC += 128; pxc += 32; py += 1024;
  }
}

extern "C" void kernel_launch(void* const* d_in, const int* in_sizes, int n_in,
                              void* d_out, int out_size, void* d_ws, size_t ws_size,
                              hipStream_t stream) {
  const float* x     = (const float*)d_in[0];
  const float* W_in  = (const float*)d_in[1];
  const float* W_xp  = (const float*)d_in[2];
  const float* W_dt  = (const float*)d_in[3];
  const float* b_dt  = (const float*)d_in[4];
  const float* W_out = (const float*)d_in[5];
  const float* b_out = (const float*)d_in[6];
  const float* W_res = (const float*)d_in[7];
  const float* A_log = (const float*)d_in[8];
  float* out = (float*)d_out;

  float* ws     = (float*)d_ws;
  float* siluxz = ws;                               // 2048*2048
  float* xp     = siluxz + (size_t)2048 * 2048;     // 2048*128
  float* dtb    = xp     + (size_t)2048 * 128;      // 2048*1024
  float* xc     = dtb    + (size_t)2048 * 1024;     // 2048*32
  float* ybuf   = xc     + (size_t)2048 * 32;       // 2048*1024

  // g1: siluxz = silu(x @ W_in.T)   M=2048 N=2048 K=1024
  gemm_wt<EPI_SILU, false><<<dim3(32, 32), 256, 0, stream>>>(
      x, 1024, nullptr, 0, W_in, 1024, nullptr, siluxz, 2048, 2048, 1024);
  // g2: xp = x_in @ W_xproj.T       N=128 K=1024
  gemm_wt<EPI_NONE, false><<<dim3(32, 2), 256, 0, stream>>>(
      siluxz, 2048, nullptr, 0, W_xp, 1024, nullptr, xp, 128, 128, 1024);
  // g3: dt = softplus(xp[:, :64] @ W_dt.T + b_dt)  N=1024 K=64
  gemm_wt<EPI_SPBIAS, false><<<dim3(32, 16), 256, 0, stream>>>(
      xp, 128, nullptr, 0, W_dt, 64, b_dt, dtb, 1024, 1024, 64);
  // g4: xc = x_in @ W_res.T         N=32 K=1024
  gemm_wt<EPI_NONE, false><<<dim3(32, 1), 256, 0, stream>>>(
      siluxz, 2048, nullptr, 0, W_res, 1024, nullptr, xc, 32, 32, 1024);
  // zero y accumulator
  zero_kernel<<<dim3(2048), 256, 0, stream>>>((float4*)ybuf, (2048 * 1024) / 4);
  // scan: 64 blocks (B*S) x 1024 threads (D)
  scan_kernel<<<dim3(64), dim3(1024), 0, stream>>>(
      siluxz, xp, dtb, xc, A_log, ybuf, 512);
  // g5: out = (y * silu(z)) @ W_out.T + b_out   N=1024 K=1024
  gemm_wt<EPI_BIAS, true><<<dim3(32, 16), 256, 0, stream>>>(
      ybuf, 1024, siluxz + 1024, 2048, W_out, 1024, b_out, out, 1024, 1024, 1024);
}

// Round 2
// 924.031 us; speedup vs baseline: 1.3608x; 1.1903x over previous
//
#include <hip/hip_runtime.h>
#include <hip/hip_bf16.h>
#include <math.h>

// CircumpunctSSM: B=4, T=512, D=1024, S=16, dt_rank=64. All f32.
// Pipeline:
//   g1: siluxz[2048,2048] = silu(x @ W_in.T)        (x_in = cols 0..1023, silu(z) = cols 1024..2047)
//   g2: xp[2048,128]      = x_in @ W_xproj.T
//   g3: dt[2048,1024]     = softplus(xp[:, :64] @ W_dt.T + b_dt)
//   g4: xc[2048,32]       = x_in @ W_res.T
//   zero y; scan (64 blocks = B*S, 256 thr x 4 elems = D): h recurrence + comp mean + y atomics
//   g5: out = (y * silu(z)) @ W_out.T + b_out

enum { EPI_NONE=0, EPI_SILU=1, EPI_SPBIAS=2, EPI_BIAS=3 };

template<int EPI>
__device__ __forceinline__ float epi_apply(float v, float b) {
  if constexpr (EPI == EPI_SILU)        { return v / (1.0f + expf(-v)); }
  else if constexpr (EPI == EPI_SPBIAS) { float t = v + b; return fmaxf(t, 0.0f) + log1pf(expf(-fabsf(t))); }
  else if constexpr (EPI == EPI_BIAS)   { return v + b; }
  else return v;
}

// C[m,n] = EPI( sum_k Aeff[m,k]*W[n,k] (+bias[n]) ), Aeff = A (elementwise * A2 if HAS_A2)
template<int EPI, bool HAS_A2>
__global__ __launch_bounds__(256) void gemm_wt(
    const float* __restrict__ A, int lda,
    const float* __restrict__ A2, int lda2,
    const float* __restrict__ W, int ldw,
    const float* __restrict__ bias,
    float* __restrict__ C, int ldc,
    int N, int K)
{
  constexpr int BM = 64, BN = 64, BK = 16, PAD = 4;
  __shared__ float As[BK][BM + PAD];
  __shared__ float Ws[BK][BN + PAD];
  const int m0 = blockIdx.x * BM;
  const int n0 = blockIdx.y * BN;
  const int tid = threadIdx.x;
  const int tx = tid & 15;        // n-direction (4 cols each)
  const int ty = tid >> 4;        // m-direction (4 rows each)
  const int lm = tid >> 2;        // 0..63 staging row
  const int lk = (tid & 3) << 2;  // 0,4,8,12 staging k (float4)

  float acc[4][4] = {{0.f,0.f,0.f,0.f},{0.f,0.f,0.f,0.f},{0.f,0.f,0.f,0.f},{0.f,0.f,0.f,0.f}};

  for (int k0 = 0; k0 < K; k0 += BK) {
    float4 av, wv;
    {
      const float* p = A + (size_t)(m0 + lm) * lda + k0 + lk;
      av = *(const float4*)p;
      if (HAS_A2) {
        const float4 a2 = *(const float4*)(A2 + (size_t)(m0 + lm) * lda2 + k0 + lk);
        av.x *= a2.x; av.y *= a2.y; av.z *= a2.z; av.w *= a2.w;
      }
    }
    {
      const int n = n0 + lm;
      if (n < N) wv = *(const float4*)(W + (size_t)n * ldw + k0 + lk);
      else       wv = make_float4(0.f, 0.f, 0.f, 0.f);
    }
    __syncthreads();   // protect previous iteration's LDS reads
    As[lk+0][lm] = av.x; As[lk+1][lm] = av.y; As[lk+2][lm] = av.z; As[lk+3][lm] = av.w;
    Ws[lk+0][lm] = wv.x; Ws[lk+1][lm] = wv.y; Ws[lk+2][lm] = wv.z; Ws[lk+3][lm] = wv.w;
    __syncthreads();
#pragma unroll
    for (int kk = 0; kk < BK; ++kk) {
      const float4 a = *(const float4*)&As[kk][ty << 2];
      const float4 w = *(const float4*)&Ws[kk][tx << 2];
      const float ar[4] = {a.x, a.y, a.z, a.w};
      const float wr[4] = {w.x, w.y, w.z, w.w};
#pragma unroll
      for (int i = 0; i < 4; ++i)
#pragma unroll
        for (int j = 0; j < 4; ++j)
          acc[i][j] = fmaf(ar[i], wr[j], acc[i][j]);
    }
  }

  const int ncol = n0 + (tx << 2);
  float bj[4] = {0.f, 0.f, 0.f, 0.f};
  if constexpr (EPI == EPI_SPBIAS || EPI == EPI_BIAS) {
    if (ncol < N) { const float4 bv = *(const float4*)(bias + ncol); bj[0]=bv.x; bj[1]=bv.y; bj[2]=bv.z; bj[3]=bv.w; }
  }
  if (ncol < N) {
#pragma unroll
    for (int i = 0; i < 4; ++i) {
      float vs[4];
#pragma unroll
      for (int j = 0; j < 4; ++j) vs[j] = epi_apply<EPI>(acc[i][j], bj[j]);
      *(float4*)(C + (size_t)(m0 + (ty << 2) + i) * ldc + ncol) = make_float4(vs[0], vs[1], vs[2], vs[3]);
    }
  }
}

__global__ void zero_kernel(float4* __restrict__ p, int n4) {
  const int i = blockIdx.x * blockDim.x + threadIdx.x;
  if (i < n4) p[i] = make_float4(0.f, 0.f, 0.f, 0.f);
}

// Scan: one block per (b,s); 256 threads x 4 consecutive d each (4 waves).
// R2 restructure vs R1 (1024 thr):
//  - 4 waves instead of 16: barrier skew /4, shuffle-tree LDS ops /4, per-thread
//    fixed costs (reduce, surfaced, d-tail, scalar loads) amortized over 4 elems,
//    4 independent element chains give ILP over the transcendental latencies.
//  - cross-wave reduce: lane0 ds_write per wave + post-barrier float4 gather
//    (replaces serialized LDS atomics + zeroing).
//  - all divisions/sqrt on hot path -> v_rsq_f32 / v_rcp_f32 single instrs.
//  - raw s_barrier with lgkmcnt-only drain (global atomics/prefetch stay in flight).
__global__ __launch_bounds__(256) void scan_kernel(
    const float* __restrict__ xin,   // siluxz base, ld 2048 (cols 0..1023 = x_in)
    const float* __restrict__ xp,    // ld 128
    const float* __restrict__ dtb,   // ld 1024
    const float* __restrict__ xc,    // ld 32
    const float* __restrict__ A_log, // [16]
    float* __restrict__ y,           // ld 1024, pre-zeroed
    int T)
{
  const int b = blockIdx.x >> 4;
  const int s = blockIdx.x & 15;
  const int d0 = threadIdx.x << 2;          // 4 consecutive d per thread
  const int lane = threadIdx.x & 63;
  const int wid = threadIdx.x >> 6;         // 0..3

  __shared__ __align__(16) float red[3][4][2];  // [buf][wave][r,i]

  const float a_s = expf(A_log[s]);
  const float phase = (float)(6.283185307179586 * (double)s / 16.0);
  float d_r = 0.01f * cosf(phase);
  float d_i = 0.01f * sinf(phase);
  float h_r[4] = {0.f,0.f,0.f,0.f};
  float h_i[4] = {0.f,0.f,0.f,0.f};

  // per-thread walking pointers (one row per step)
  const size_t rb = (size_t)b * T;
  const float* px  = xin + rb * 2048 + d0;
  const float* pdt = dtb + rb * 1024 + d0;
  const float* pB  = xp  + rb * 128 + 64 + 2 * s;
  const float* pC  = xp  + rb * 128 + 96 + 2 * s;
  const float* pxc = xc  + rb * 32 + 2 * s;
  float*       py  = y   + rb * 1024 + d0;

  // preload t=0
  float4 xv  = *(const float4*)px;
  float4 dtv = *(const float4*)pdt;
  float2 Bv  = *(const float2*)pB;
  float2 Cv  = *(const float2*)pC;
  float2 xcv = *(const float2*)pxc;

  int tb = 0;  // t % 3 without the magic-mul

  for (int t = 0; t < T; ++t) {
    const float xa[4]  = {xv.x, xv.y, xv.z, xv.w};
    const float dta[4] = {dtv.x, dtv.y, dtv.z, dtv.w};
    float alpha[4];
    float w_r = 0.f, w_i = 0.f;

    // comp from released(h_prev, alpha), 4 independent chains
#pragma unroll
    for (int e = 0; e < 4; ++e) {
      alpha[e] = __expf(-dta[e] * a_s);
      const float om    = 1.0f - alpha[e];
      const float rel_r = h_r[e] * om, rel_i = h_i[e] * om;
      const float m2 = fmaf(rel_r, rel_r, fmaf(rel_i, rel_i, 1e-8f));
      const float cm = exp2f(log2f(m2) * (1.0f / 3.0f));     // mag^(2/3)
      const float rr = rel_r + 1e-10f;
      const float invr = __builtin_amdgcn_rsqf(fmaf(rr, rr, fmaf(rel_i, rel_i, 1e-38f)));
      float c_r = cm * rr * invr;    c_r = fminf(fmaxf(c_r, -10.f), 10.f);
      float c_i = cm * rel_i * invr; c_i = fminf(fmaxf(c_i, -10.f), 10.f);
      w_r += c_r; w_i += c_i;
    }

    // wave butterfly reduce (two interleaved chains)
#pragma unroll
    for (int o = 32; o; o >>= 1) { w_r += __shfl_xor(w_r, o); w_i += __shfl_xor(w_i, o); }
    if (lane == 0) *(float2*)&red[tb][wid][0] = make_float2(w_r, w_i);

    // prefetch t+1 inputs NOW — they stay in flight across the raw barrier.
    // (At t==T-1 these read one row past each logical buffer; all such reads
    //  land inside the workspace allocation and the values are never used.)
    const float4 xv_n  = *(const float4*)(px + 2048);
    const float4 dtv_n = *(const float4*)(pdt + 1024);
    const float2 Bv_n  = *(const float2*)(pB + 128);
    const float2 Cv_n  = *(const float2*)(pC + 128);
    const float2 xcv_n = *(const float2*)(pxc + 32);

    // surfaced from d_prev (uniform per thread) + x_complex
    const float xr2 = xcv.x + 1e-10f;
    const float irx = __builtin_amdgcn_rsqf(fmaf(xr2, xr2, fmaf(xcv.y, xcv.y, 1e-38f)));
    const float dr2 = d_r + 1e-10f;
    const float ird = __builtin_amdgcn_rsqf(fmaf(dr2, dr2, fmaf(d_i, d_i, 1e-38f)));
    const float cosdp = fmaf(xr2, dr2, xcv.y * d_i) * irx * ird;
    const float Tg  = 0.5f * (1.0f + cosdp);                  // cos^2((phix-phid)/2)
    const float md2  = fmaf(d_r, d_r, fmaf(d_i, d_i, 1e-8f));
    const float irm  = __builtin_amdgcn_rsqf(md2);
    const float dmag = md2 * irm;                             // sqrt(md2)
    const float cl   = fminf(fmaxf(dmag, 1e-6f), 20.f);
    const float dscale = cl * __builtin_amdgcn_rsqf(cl);      // sqrt(cl)
    const float sfac = dscale * Tg * __builtin_amdgcn_rcpf(dmag + 1e-8f);
    const float s_r = d_r * sfac, s_i = d_i * sfac;

    // h update + y contribution (fire-and-forget atomics, never drained)
#pragma unroll
    for (int e = 0; e < 4; ++e) {
      const float bx_r = fmaf(Bv.x, xa[e], s_r) * dta[e];
      const float bx_i = fmaf(Bv.y, xa[e], s_i) * dta[e];
      h_r[e] = fmaf(h_r[e], alpha[e], bx_r);
      h_i[e] = fmaf(h_i[e], alpha[e], bx_i);
      atomicAdd(py + e, fmaf(Cv.x, h_r[e], -(Cv.y * h_i[e])));
    }

    // raw barrier: drain LDS ops only; global loads/atomics stay in flight
    asm volatile("s_waitcnt lgkmcnt(0)" ::: "memory");
    __builtin_amdgcn_s_barrier();
    asm volatile("" ::: "memory");

    // gather 4 wave sums (broadcast LDS reads) -> d update
    const float4 q0 = *(const float4*)&red[tb][0][0];
    const float4 q1 = *(const float4*)&red[tb][2][0];
    const float avg_r = (q0.x + q0.z + q1.x + q1.z) * (1.0f / 1024.0f);
    const float avg_i = (q0.y + q0.w + q1.y + q1.w) * (1.0f / 1024.0f);
    d_r = fmaf(0.01f, avg_r, d_r);
    d_i = fmaf(0.01f, avg_i, d_i);
    const float dm2 = fmaf(d_r, d_r, fmaf(d_i, d_i, 1e-8f));
    if (dm2 > 400.f) { const float sc = 20.f * __builtin_amdgcn_rsqf(dm2); d_r *= sc; d_i *= sc; }

    // rotate prefetched state, advance pointers
    xv = xv_n; dtv = dtv_n; Bv = Bv_n; Cv = Cv_n; xcv = xcv_n;
    px += 2048; pdt += 1024; pB += 128; pC += 128; pxc += 32; py += 1024;
    tb = (tb == 2) ? 0 : tb + 1;
  }
}

extern "C" void kernel_launch(void* const* d_in, const int* in_sizes, int n_in,
                              void* d_out, int out_size, void* d_ws, size_t ws_size,
                              hipStream_t stream) {
  const float* x     = (const float*)d_in[0];
  const float* W_in  = (const float*)d_in[1];
  const float* W_xp  = (const float*)d_in[2];
  const float* W_dt  = (const float*)d_in[3];
  const float* b_dt  = (const float*)d_in[4];
  const float* W_out = (const float*)d_in[5];
  const float* b_out = (const float*)d_in[6];
  const float* W_res = (const float*)d_in[7];
  const float* A_log = (const float*)d_in[8];
  float* out = (float*)d_out;

  float* ws     = (float*)d_ws;
  float* siluxz = ws;                               // 2048*2048
  float* xp     = siluxz + (size_t)2048 * 2048;     // 2048*128
  float* dtb    = xp     + (size_t)2048 * 128;      // 2048*1024
  float* xc     = dtb    + (size_t)2048 * 1024;     // 2048*32
  float* ybuf   = xc     + (size_t)2048 * 32;       // 2048*1024

  // g1: siluxz = silu(x @ W_in.T)   M=2048 N=2048 K=1024
  gemm_wt<EPI_SILU, false><<<dim3(32, 32), 256, 0, stream>>>(
      x, 1024, nullptr, 0, W_in, 1024, nullptr, siluxz, 2048, 2048, 1024);
  // g2: xp = x_in @ W_xproj.T       N=128 K=1024
  gemm_wt<EPI_NONE, false><<<dim3(32, 2), 256, 0, stream>>>(
      siluxz, 2048, nullptr, 0, W_xp, 1024, nullptr, xp, 128, 128, 1024);
  // g3: dt = softplus(xp[:, :64] @ W_dt.T + b_dt)  N=1024 K=64
  gemm_wt<EPI_SPBIAS, false><<<dim3(32, 16), 256, 0, stream>>>(
      xp, 128, nullptr, 0, W_dt, 64, b_dt, dtb, 1024, 1024, 64);
  // g4: xc = x_in @ W_res.T         N=32 K=1024
  gemm_wt<EPI_NONE, false><<<dim3(32, 1), 256, 0, stream>>>(
      siluxz, 2048, nullptr, 0, W_res, 1024, nullptr, xc, 32, 32, 1024);
  // zero y accumulator
  zero_kernel<<<dim3(2048), 256, 0, stream>>>((float4*)ybuf, (2048 * 1024) / 4);
  // scan: 64 blocks (B*S) x 256 threads (D/4)
  scan_kernel<<<dim3(64), dim3(256), 0, stream>>>(
      siluxz, xp, dtb, xc, A_log, ybuf, 512);
  // g5: out = (y * silu(z)) @ W_out.T + b_out   N=1024 K=1024
  gemm_wt<EPI_BIAS, true><<<dim3(32, 16), 256, 0, stream>>>(
      ybuf, 1024, siluxz + 1024, 2048, W_out, 1024, b_out, out, 1024, 1024, 1024);
}

// Round 3
// 869.359 us; speedup vs baseline: 1.4464x; 1.0629x over previous
//
#include <hip/hip_runtime.h>
#include <hip/hip_bf16.h>
#include <math.h>

// CircumpunctSSM: B=4, T=512, D=1024, S=16, dt_rank=64. All f32.
// Pipeline:
//   g1: siluxz[2048,2048] = silu(x @ W_in.T)        (x_in = cols 0..1023, silu(z) = cols 1024..2047)
//   g2: xp[2048,128]      = x_in @ W_xproj.T
//   g3: dt[2048,1024]     = softplus(xp[:, :64] @ W_dt.T + b_dt)
//   g4: xc[2048,32]       = x_in @ W_res.T
//   scan (64 blocks = B*S, 256 thr x 4 elems = D): h recurrence + comp mean; y partials -> plain stores
//   reduce_y: ybuf = sum_s ypart[s]
//   g5: out = (y * silu(z)) @ W_out.T + b_out

enum { EPI_NONE=0, EPI_SILU=1, EPI_SPBIAS=2, EPI_BIAS=3 };

template<int EPI>
__device__ __forceinline__ float epi_apply(float v, float b) {
  if constexpr (EPI == EPI_SILU)        { return v / (1.0f + expf(-v)); }
  else if constexpr (EPI == EPI_SPBIAS) { float t = v + b; return fmaxf(t, 0.0f) + log1pf(expf(-fabsf(t))); }
  else if constexpr (EPI == EPI_BIAS)   { return v + b; }
  else return v;
}

// C[m,n] = EPI( sum_k Aeff[m,k]*W[n,k] (+bias[n]) ), Aeff = A (elementwise * A2 if HAS_A2)
template<int EPI, bool HAS_A2>
__global__ __launch_bounds__(256) void gemm_wt(
    const float* __restrict__ A, int lda,
    const float* __restrict__ A2, int lda2,
    const float* __restrict__ W, int ldw,
    const float* __restrict__ bias,
    float* __restrict__ C, int ldc,
    int N, int K)
{
  constexpr int BM = 64, BN = 64, BK = 16, PAD = 4;
  __shared__ float As[BK][BM + PAD];
  __shared__ float Ws[BK][BN + PAD];
  const int m0 = blockIdx.x * BM;
  const int n0 = blockIdx.y * BN;
  const int tid = threadIdx.x;
  const int tx = tid & 15;        // n-direction (4 cols each)
  const int ty = tid >> 4;        // m-direction (4 rows each)
  const int lm = tid >> 2;        // 0..63 staging row
  const int lk = (tid & 3) << 2;  // 0,4,8,12 staging k (float4)

  float acc[4][4] = {{0.f,0.f,0.f,0.f},{0.f,0.f,0.f,0.f},{0.f,0.f,0.f,0.f},{0.f,0.f,0.f,0.f}};

  for (int k0 = 0; k0 < K; k0 += BK) {
    float4 av, wv;
    {
      const float* p = A + (size_t)(m0 + lm) * lda + k0 + lk;
      av = *(const float4*)p;
      if (HAS_A2) {
        const float4 a2 = *(const float4*)(A2 + (size_t)(m0 + lm) * lda2 + k0 + lk);
        av.x *= a2.x; av.y *= a2.y; av.z *= a2.z; av.w *= a2.w;
      }
    }
    {
      const int n = n0 + lm;
      if (n < N) wv = *(const float4*)(W + (size_t)n * ldw + k0 + lk);
      else       wv = make_float4(0.f, 0.f, 0.f, 0.f);
    }
    __syncthreads();   // protect previous iteration's LDS reads
    As[lk+0][lm] = av.x; As[lk+1][lm] = av.y; As[lk+2][lm] = av.z; As[lk+3][lm] = av.w;
    Ws[lk+0][lm] = wv.x; Ws[lk+1][lm] = wv.y; Ws[lk+2][lm] = wv.z; Ws[lk+3][lm] = wv.w;
    __syncthreads();
#pragma unroll
    for (int kk = 0; kk < BK; ++kk) {
      const float4 a = *(const float4*)&As[kk][ty << 2];
      const float4 w = *(const float4*)&Ws[kk][tx << 2];
      const float ar[4] = {a.x, a.y, a.z, a.w};
      const float wr[4] = {w.x, w.y, w.z, w.w};
#pragma unroll
      for (int i = 0; i < 4; ++i)
#pragma unroll
        for (int j = 0; j < 4; ++j)
          acc[i][j] = fmaf(ar[i], wr[j], acc[i][j]);
    }
  }

  const int ncol = n0 + (tx << 2);
  float bj[4] = {0.f, 0.f, 0.f, 0.f};
  if constexpr (EPI == EPI_SPBIAS || EPI == EPI_BIAS) {
    if (ncol < N) { const float4 bv = *(const float4*)(bias + ncol); bj[0]=bv.x; bj[1]=bv.y; bj[2]=bv.z; bj[3]=bv.w; }
  }
  if (ncol < N) {
#pragma unroll
    for (int i = 0; i < 4; ++i) {
      float vs[4];
#pragma unroll
      for (int j = 0; j < 4; ++j) vs[j] = epi_apply<EPI>(acc[i][j], bj[j]);
      *(float4*)(C + (size_t)(m0 + (ty << 2) + i) * ldc + ncol) = make_float4(vs[0], vs[1], vs[2], vs[3]);
    }
  }
}

__global__ void zero_kernel(float4* __restrict__ p, int n4) {
  const int i = blockIdx.x * blockDim.x + threadIdx.x;
  if (i < n4) p[i] = make_float4(0.f, 0.f, 0.f, 0.f);
}

// ybuf[i] = sum_s ypart[s][i]  (i over B*T*D float4s; per-s chunk = 524288 float4)
__global__ __launch_bounds__(256) void reduce_y(const float4* __restrict__ yp, float4* __restrict__ yo, int n4) {
  const int i = blockIdx.x * blockDim.x + threadIdx.x;
  if (i >= n4) return;
  float4 a = yp[i];
#pragma unroll
  for (int s = 1; s < 16; ++s) {
    const float4 v = yp[(size_t)s * 524288 + i];
    a.x += v.x; a.y += v.y; a.z += v.z; a.w += v.w;
  }
  yo[i] = a;
}

// Scan: one block per (b,s); 256 threads x 4 consecutive d each (4 waves).
// R3 change: y contributions go to a PRIVATE per-s partial buffer via plain
// coalesced float4 stores (PARTIAL=true) instead of 16-way cross-XCD atomics.
// R2 counters showed the atomics caused 4x HBM write amplification (512 MB) and,
// via in-order vmcnt retirement, put contended-atomic latency on the per-step
// wait chain. Plain stores retire at streaming BW and are never waited on
// (prefetch loads are issued BEFORE the store each step, so consuming them
// next step leaves the store outstanding with 2 steps of slack).
// PARTIAL=false is the R2 atomic fallback if ws_size can't fit the partials.
template<bool PARTIAL>
__global__ __launch_bounds__(256) void scan_kernel(
    const float* __restrict__ xin,   // siluxz base, ld 2048 (cols 0..1023 = x_in)
    const float* __restrict__ xp,    // ld 128
    const float* __restrict__ dtb,   // ld 1024
    const float* __restrict__ xc,    // ld 32
    const float* __restrict__ A_log, // [16]
    float* __restrict__ ybase,       // PARTIAL ? ypart[16][B*T*D] : y (pre-zeroed), ld 1024
    int T)
{
  const int b = blockIdx.x >> 4;
  const int s = blockIdx.x & 15;
  const int d0 = threadIdx.x << 2;          // 4 consecutive d per thread
  const int lane = threadIdx.x & 63;
  const int wid = threadIdx.x >> 6;         // 0..3

  __shared__ __align__(16) float red[3][4][2];  // [buf][wave][r,i]

  const float a_s = expf(A_log[s]);
  const float phase = (float)(6.283185307179586 * (double)s / 16.0);
  float d_r = 0.01f * cosf(phase);
  float d_i = 0.01f * sinf(phase);
  float h_r[4] = {0.f,0.f,0.f,0.f};
  float h_i[4] = {0.f,0.f,0.f,0.f};

  // per-thread walking pointers (one row per step)
  const size_t rb = (size_t)b * T;
  const float* px  = xin + rb * 2048 + d0;
  const float* pdt = dtb + rb * 1024 + d0;
  const float* pB  = xp  + rb * 128 + 64 + 2 * s;
  const float* pC  = xp  + rb * 128 + 96 + 2 * s;
  const float* pxc = xc  + rb * 32 + 2 * s;
  float* py = PARTIAL ? (ybase + (size_t)s * (4 * 512 * 1024) + rb * 1024 + d0)
                      : (ybase + rb * 1024 + d0);

  // preload t=0
  float4 xv  = *(const float4*)px;
  float4 dtv = *(const float4*)pdt;
  float2 Bv  = *(const float2*)pB;
  float2 Cv  = *(const float2*)pC;
  float2 xcv = *(const float2*)pxc;

  int tb = 0;  // t % 3

  for (int t = 0; t < T; ++t) {
    const float xa[4]  = {xv.x, xv.y, xv.z, xv.w};
    const float dta[4] = {dtv.x, dtv.y, dtv.z, dtv.w};
    float alpha[4];
    float w_r = 0.f, w_i = 0.f;

    // comp from released(h_prev, alpha), 4 independent chains
#pragma unroll
    for (int e = 0; e < 4; ++e) {
      alpha[e] = __expf(-dta[e] * a_s);
      const float om    = 1.0f - alpha[e];
      const float rel_r = h_r[e] * om, rel_i = h_i[e] * om;
      const float m2 = fmaf(rel_r, rel_r, fmaf(rel_i, rel_i, 1e-8f));
      const float cm = exp2f(log2f(m2) * (1.0f / 3.0f));     // mag^(2/3)
      const float rr = rel_r + 1e-10f;
      const float invr = __builtin_amdgcn_rsqf(fmaf(rr, rr, fmaf(rel_i, rel_i, 1e-38f)));
      float c_r = cm * rr * invr;    c_r = fminf(fmaxf(c_r, -10.f), 10.f);
      float c_i = cm * rel_i * invr; c_i = fminf(fmaxf(c_i, -10.f), 10.f);
      w_r += c_r; w_i += c_i;
    }

    // wave butterfly reduce (two interleaved chains)
#pragma unroll
    for (int o = 32; o; o >>= 1) { w_r += __shfl_xor(w_r, o); w_i += __shfl_xor(w_i, o); }
    if (lane == 0) *(float2*)&red[tb][wid][0] = make_float2(w_r, w_i);

    // prefetch t+1 inputs NOW — stay in flight across the raw barrier.
    // (At t==T-1 these read one row past each logical buffer; all such reads
    //  land inside the workspace allocation and the values are never used.)
    const float4 xv_n  = *(const float4*)(px + 2048);
    const float4 dtv_n = *(const float4*)(pdt + 1024);
    const float2 Bv_n  = *(const float2*)(pB + 128);
    const float2 Cv_n  = *(const float2*)(pC + 128);
    const float2 xcv_n = *(const float2*)(pxc + 32);

    // surfaced from d_prev (uniform per thread) + x_complex
    const float xr2 = xcv.x + 1e-10f;
    const float irx = __builtin_amdgcn_rsqf(fmaf(xr2, xr2, fmaf(xcv.y, xcv.y, 1e-38f)));
    const float dr2 = d_r + 1e-10f;
    const float ird = __builtin_amdgcn_rsqf(fmaf(dr2, dr2, fmaf(d_i, d_i, 1e-38f)));
    const float cosdp = fmaf(xr2, dr2, xcv.y * d_i) * irx * ird;
    const float Tg  = 0.5f * (1.0f + cosdp);                  // cos^2((phix-phid)/2)
    const float md2  = fmaf(d_r, d_r, fmaf(d_i, d_i, 1e-8f));
    const float irm  = __builtin_amdgcn_rsqf(md2);
    const float dmag = md2 * irm;                             // sqrt(md2)
    const float cl   = fminf(fmaxf(dmag, 1e-6f), 20.f);
    const float dscale = cl * __builtin_amdgcn_rsqf(cl);      // sqrt(cl)
    const float sfac = dscale * Tg * __builtin_amdgcn_rcpf(dmag + 1e-8f);
    const float s_r = d_r * sfac, s_i = d_i * sfac;

    // h update + y contribution
    float yv[4];
#pragma unroll
    for (int e = 0; e < 4; ++e) {
      const float bx_r = fmaf(Bv.x, xa[e], s_r) * dta[e];
      const float bx_i = fmaf(Bv.y, xa[e], s_i) * dta[e];
      h_r[e] = fmaf(h_r[e], alpha[e], bx_r);
      h_i[e] = fmaf(h_i[e], alpha[e], bx_i);
      yv[e] = fmaf(Cv.x, h_r[e], -(Cv.y * h_i[e]));
    }
    if (PARTIAL) {
      *(float4*)py = make_float4(yv[0], yv[1], yv[2], yv[3]);   // private buffer, no contention
    } else {
#pragma unroll
      for (int e = 0; e < 4; ++e) atomicAdd(py + e, yv[e]);
    }

    // raw barrier: drain LDS ops only; global loads/stores stay in flight
    asm volatile("s_waitcnt lgkmcnt(0)" ::: "memory");
    __builtin_amdgcn_s_barrier();
    asm volatile("" ::: "memory");

    // gather 4 wave sums (broadcast LDS reads) -> d update
    const float4 q0 = *(const float4*)&red[tb][0][0];
    const float4 q1 = *(const float4*)&red[tb][2][0];
    const float avg_r = (q0.x + q0.z + q1.x + q1.z) * (1.0f / 1024.0f);
    const float avg_i = (q0.y + q0.w + q1.y + q1.w) * (1.0f / 1024.0f);
    d_r = fmaf(0.01f, avg_r, d_r);
    d_i = fmaf(0.01f, avg_i, d_i);
    const float dm2 = fmaf(d_r, d_r, fmaf(d_i, d_i, 1e-8f));
    if (dm2 > 400.f) { const float sc = 20.f * __builtin_amdgcn_rsqf(dm2); d_r *= sc; d_i *= sc; }

    // rotate prefetched state, advance pointers
    xv = xv_n; dtv = dtv_n; Bv = Bv_n; Cv = Cv_n; xcv = xcv_n;
    px += 2048; pdt += 1024; pB += 128; pC += 128; pxc += 32; py += 1024;
    tb = (tb == 2) ? 0 : tb + 1;
  }
}

extern "C" void kernel_launch(void* const* d_in, const int* in_sizes, int n_in,
                              void* d_out, int out_size, void* d_ws, size_t ws_size,
                              hipStream_t stream) {
  const float* x     = (const float*)d_in[0];
  const float* W_in  = (const float*)d_in[1];
  const float* W_xp  = (const float*)d_in[2];
  const float* W_dt  = (const float*)d_in[3];
  const float* b_dt  = (const float*)d_in[4];
  const float* W_out = (const float*)d_in[5];
  const float* b_out = (const float*)d_in[6];
  const float* W_res = (const float*)d_in[7];
  const float* A_log = (const float*)d_in[8];
  float* out = (float*)d_out;

  float* ws     = (float*)d_ws;
  float* siluxz = ws;                               // 2048*2048   = 4,194,304 f
  float* xp     = siluxz + (size_t)2048 * 2048;     // 2048*128    =   262,144 f
  float* dtb    = xp     + (size_t)2048 * 128;      // 2048*1024   = 2,097,152 f
  float* xc     = dtb    + (size_t)2048 * 1024;     // 2048*32     =    65,536 f
  float* ybuf   = xc     + (size_t)2048 * 32;       // 2048*1024   = 2,097,152 f
  float* ypart  = ybuf   + (size_t)2048 * 1024;     // 16*2048*1024 = 33,554,432 f (if it fits)

  const size_t need_bytes = ((size_t)8716288 + (size_t)33554432) * 4;  // base + ypart
  const bool use_part = ws_size >= need_bytes;

  // g1: siluxz = silu(x @ W_in.T)   M=2048 N=2048 K=1024
  gemm_wt<EPI_SILU, false><<<dim3(32, 32), 256, 0, stream>>>(
      x, 1024, nullptr, 0, W_in, 1024, nullptr, siluxz, 2048, 2048, 1024);
  // g2: xp = x_in @ W_xproj.T       N=128 K=1024
  gemm_wt<EPI_NONE, false><<<dim3(32, 2), 256, 0, stream>>>(
      siluxz, 2048, nullptr, 0, W_xp, 1024, nullptr, xp, 128, 128, 1024);
  // g3: dt = softplus(xp[:, :64] @ W_dt.T + b_dt)  N=1024 K=64
  gemm_wt<EPI_SPBIAS, false><<<dim3(32, 16), 256, 0, stream>>>(
      xp, 128, nullptr, 0, W_dt, 64, b_dt, dtb, 1024, 1024, 64);
  // g4: xc = x_in @ W_res.T         N=32 K=1024
  gemm_wt<EPI_NONE, false><<<dim3(32, 1), 256, 0, stream>>>(
      siluxz, 2048, nullptr, 0, W_res, 1024, nullptr, xc, 32, 32, 1024);

  if (use_part) {
    // scan writes private partials (plain stores); then fold over s
    scan_kernel<true><<<dim3(64), dim3(256), 0, stream>>>(
        siluxz, xp, dtb, xc, A_log, ypart, 512);
    reduce_y<<<dim3(2048), 256, 0, stream>>>((const float4*)ypart, (float4*)ybuf, 524288);
  } else {
    // fallback: atomic accumulation into pre-zeroed ybuf
    zero_kernel<<<dim3(2048), 256, 0, stream>>>((float4*)ybuf, (2048 * 1024) / 4);
    scan_kernel<false><<<dim3(64), dim3(256), 0, stream>>>(
        siluxz, xp, dtb, xc, A_log, ybuf, 512);
  }

  // g5: out = (y * silu(z)) @ W_out.T + b_out   N=1024 K=1024
  gemm_wt<EPI_BIAS, true><<<dim3(32, 16), 256, 0, stream>>>(
      ybuf, 1024, siluxz + 1024, 2048, W_out, 1024, b_out, out, 1024, 1024, 1024);
}

// Round 4
// 695.368 us; speedup vs baseline: 1.8083x; 1.2502x over previous
//
#include <hip/hip_runtime.h>
#include <hip/hip_bf16.h>
#include <math.h>

// CircumpunctSSM: B=4, T=512, D=1024, S=16, dt_rank=64. All f32.
// Pipeline:
//   g1: siluxz[2048,2048] = silu(x @ W_in.T)        (x_in = cols 0..1023, silu(z) = cols 1024..2047)
//   g2: xp[2048,128]      = x_in @ W_xproj.T
//   g3: dt[2048,1024]     = softplus(xp[:, :64] @ W_dt.T + b_dt)
//   g4: xc[2048,32]       = x_in @ W_res.T
//   scan (64 blocks = B*S, 256 thr x 4 elems = D): h recurrence + comp mean; y partials -> plain stores
//   reduce_y: ybuf = sum_s ypart[s]
//   g5: out = (y * silu(z)) @ W_out.T + b_out

enum { EPI_NONE=0, EPI_SILU=1, EPI_SPBIAS=2, EPI_BIAS=3 };

template<int EPI>
__device__ __forceinline__ float epi_apply(float v, float b) {
  if constexpr (EPI == EPI_SILU)        { return v / (1.0f + expf(-v)); }
  else if constexpr (EPI == EPI_SPBIAS) { float t = v + b; return fmaxf(t, 0.0f) + log1pf(expf(-fabsf(t))); }
  else if constexpr (EPI == EPI_BIAS)   { return v + b; }
  else return v;
}

// C[m,n] = EPI( sum_k Aeff[m,k]*W[n,k] (+bias[n]) ), Aeff = A (elementwise * A2 if HAS_A2)
template<int EPI, bool HAS_A2>
__global__ __launch_bounds__(256) void gemm_wt(
    const float* __restrict__ A, int lda,
    const float* __restrict__ A2, int lda2,
    const float* __restrict__ W, int ldw,
    const float* __restrict__ bias,
    float* __restrict__ C, int ldc,
    int N, int K)
{
  constexpr int BM = 64, BN = 64, BK = 16, PAD = 4;
  __shared__ float As[BK][BM + PAD];
  __shared__ float Ws[BK][BN + PAD];
  const int m0 = blockIdx.x * BM;
  const int n0 = blockIdx.y * BN;
  const int tid = threadIdx.x;
  const int tx = tid & 15;        // n-direction (4 cols each)
  const int ty = tid >> 4;        // m-direction (4 rows each)
  const int lm = tid >> 2;        // 0..63 staging row
  const int lk = (tid & 3) << 2;  // 0,4,8,12 staging k (float4)

  float acc[4][4] = {{0.f,0.f,0.f,0.f},{0.f,0.f,0.f,0.f},{0.f,0.f,0.f,0.f},{0.f,0.f,0.f,0.f}};

  for (int k0 = 0; k0 < K; k0 += BK) {
    float4 av, wv;
    {
      const float* p = A + (size_t)(m0 + lm) * lda + k0 + lk;
      av = *(const float4*)p;
      if (HAS_A2) {
        const float4 a2 = *(const float4*)(A2 + (size_t)(m0 + lm) * lda2 + k0 + lk);
        av.x *= a2.x; av.y *= a2.y; av.z *= a2.z; av.w *= a2.w;
      }
    }
    {
      const int n = n0 + lm;
      if (n < N) wv = *(const float4*)(W + (size_t)n * ldw + k0 + lk);
      else       wv = make_float4(0.f, 0.f, 0.f, 0.f);
    }
    __syncthreads();   // protect previous iteration's LDS reads
    As[lk+0][lm] = av.x; As[lk+1][lm] = av.y; As[lk+2][lm] = av.z; As[lk+3][lm] = av.w;
    Ws[lk+0][lm] = wv.x; Ws[lk+1][lm] = wv.y; Ws[lk+2][lm] = wv.z; Ws[lk+3][lm] = wv.w;
    __syncthreads();
#pragma unroll
    for (int kk = 0; kk < BK; ++kk) {
      const float4 a = *(const float4*)&As[kk][ty << 2];
      const float4 w = *(const float4*)&Ws[kk][tx << 2];
      const float ar[4] = {a.x, a.y, a.z, a.w};
      const float wr[4] = {w.x, w.y, w.z, w.w};
#pragma unroll
      for (int i = 0; i < 4; ++i)
#pragma unroll
        for (int j = 0; j < 4; ++j)
          acc[i][j] = fmaf(ar[i], wr[j], acc[i][j]);
    }
  }

  const int ncol = n0 + (tx << 2);
  float bj[4] = {0.f, 0.f, 0.f, 0.f};
  if constexpr (EPI == EPI_SPBIAS || EPI == EPI_BIAS) {
    if (ncol < N) { const float4 bv = *(const float4*)(bias + ncol); bj[0]=bv.x; bj[1]=bv.y; bj[2]=bv.z; bj[3]=bv.w; }
  }
  if (ncol < N) {
#pragma unroll
    for (int i = 0; i < 4; ++i) {
      float vs[4];
#pragma unroll
      for (int j = 0; j < 4; ++j) vs[j] = epi_apply<EPI>(acc[i][j], bj[j]);
      *(float4*)(C + (size_t)(m0 + (ty << 2) + i) * ldc + ncol) = make_float4(vs[0], vs[1], vs[2], vs[3]);
    }
  }
}

__global__ void zero_kernel(float4* __restrict__ p, int n4) {
  const int i = blockIdx.x * blockDim.x + threadIdx.x;
  if (i < n4) p[i] = make_float4(0.f, 0.f, 0.f, 0.f);
}

// ybuf[i] = sum_s ypart[s][i]  (i over B*T*D float4s; per-s chunk = 524288 float4)
__global__ __launch_bounds__(256) void reduce_y(const float4* __restrict__ yp, float4* __restrict__ yo, int n4) {
  const int i = blockIdx.x * blockDim.x + threadIdx.x;
  if (i >= n4) return;
  float4 a = yp[i];
#pragma unroll
  for (int s = 1; s < 16; ++s) {
    const float4 v = yp[(size_t)s * 524288 + i];
    a.x += v.x; a.y += v.y; a.z += v.z; a.w += v.w;
  }
  yo[i] = a;
}

// --- DPP wave64 sum: 6 dependent full-rate VALU adds (~60 cyc total) instead of
// --- 6 dependent DS shuffle ops (~700 cyc). Classic gfx9 sequence:
// --- row_shr 1/2/4/8 builds per-row(16) prefix sums; row_bcast15 merges row pairs;
// --- row_bcast31 merges 32-halves. Lane 63 ends with the full 64-lane sum
// --- (only lane 63's value is consumed, so other lanes' partials don't matter).
template<int CTRL>
__device__ __forceinline__ float dpp_fadd(float x) {
  const int s = __builtin_amdgcn_update_dpp(0, __float_as_int(x), CTRL, 0xF, 0xF, true);
  return x + __int_as_float(s);
}
__device__ __forceinline__ float wave64_sum_l63(float x) {
  x = dpp_fadd<0x111>(x);   // row_shr:1
  x = dpp_fadd<0x112>(x);   // row_shr:2
  x = dpp_fadd<0x114>(x);   // row_shr:4
  x = dpp_fadd<0x118>(x);   // row_shr:8
  x = dpp_fadd<0x142>(x);   // row_bcast:15
  x = dpp_fadd<0x143>(x);   // row_bcast:31
  return x;                 // lane 63 = full sum
}

// Scan: one block per (b,s); 256 threads x 4 consecutive d each (4 waves).
// R4: the step is bound by the per-wave serial chain (1 wave/SIMD -> all latency
// exposed; steps are sequential so co-residency can't help). Changes:
//  - shuffle butterfly (6x ~110cyc DS ops) -> DPP VALU reduce (~60 cyc).
//  - software-rotated schedule: read red[(t-1)%3] at loop TOP right after the
//    previous barrier; comp+DPP (independent of d) overlap the ds_read latency;
//    then d-update -> surfaced -> h. Same semantics: surfaced(t) uses
//    d(t-1) = d + 0.01*avg(comp(t-1)); t=0 reads a pre-zeroed buffer (d += 0).
//  - prefetch depth 2 (row t+2): step shrinks below HBM-miss latency, so 1-step
//    lookahead no longer covers the ~13% of loads that miss L2/L3.
//    (At t>=T-2 these read <=2 rows past each logical buffer; all land inside
//     the workspace allocation and the values are never used.)
template<bool PARTIAL>
__global__ __launch_bounds__(256) void scan_kernel(
    const float* __restrict__ xin,   // siluxz base, ld 2048 (cols 0..1023 = x_in)
    const float* __restrict__ xp,    // ld 128
    const float* __restrict__ dtb,   // ld 1024
    const float* __restrict__ xc,    // ld 32
    const float* __restrict__ A_log, // [16]
    float* __restrict__ ybase,       // PARTIAL ? ypart[16][B*T*D] : y (pre-zeroed), ld 1024
    int T)
{
  const int b = blockIdx.x >> 4;
  const int s = blockIdx.x & 15;
  const int d0 = threadIdx.x << 2;          // 4 consecutive d per thread
  const int lane = threadIdx.x & 63;
  const int wid = threadIdx.x >> 6;         // 0..3

  __shared__ __align__(16) float red[3][4][2];  // [buf][wave][r,i]
  if (threadIdx.x < 24) ((float*)red)[threadIdx.x] = 0.f;  // all 3 buffers zeroed

  const float a_s = expf(A_log[s]);
  const float phase = (float)(6.283185307179586 * (double)s / 16.0);
  float d_r = 0.01f * cosf(phase);
  float d_i = 0.01f * sinf(phase);
  float h_r[4] = {0.f,0.f,0.f,0.f};
  float h_i[4] = {0.f,0.f,0.f,0.f};
  __syncthreads();

  // per-thread walking pointers (one row per step)
  const size_t rb = (size_t)b * T;
  const float* px  = xin + rb * 2048 + d0;
  const float* pdt = dtb + rb * 1024 + d0;
  const float* pB  = xp  + rb * 128 + 64 + 2 * s;
  const float* pC  = xp  + rb * 128 + 96 + 2 * s;
  const float* pxc = xc  + rb * 32 + 2 * s;
  float* py = PARTIAL ? (ybase + (size_t)s * (4 * 512 * 1024) + rb * 1024 + d0)
                      : (ybase + rb * 1024 + d0);

  // preload rows t=0 (cur) and t=1 (nxt)
  float4 xv   = *(const float4*)px;
  float4 dtv  = *(const float4*)pdt;
  float2 Bv   = *(const float2*)pB;
  float2 Cv   = *(const float2*)pC;
  float2 xcv  = *(const float2*)pxc;
  float4 xvn  = *(const float4*)(px + 2048);
  float4 dtvn = *(const float4*)(pdt + 1024);
  float2 Bvn  = *(const float2*)(pB + 128);
  float2 Cvn  = *(const float2*)(pC + 128);
  float2 xcvn = *(const float2*)(pxc + 32);

  int cb = 0, pb = 2;  // write buffer t%3, read buffer (t-1)%3 (t=0 reads zeros)

  for (int t = 0; t < T; ++t) {
    // 1. prefetch t+2 (longest possible lead over consumption)
    const float4 xv2  = *(const float4*)(px + 2 * 2048);
    const float4 dtv2 = *(const float4*)(pdt + 2 * 1024);
    const float2 Bv2  = *(const float2*)(pB + 2 * 128);
    const float2 Cv2  = *(const float2*)(pC + 2 * 128);
    const float2 xcv2 = *(const float2*)(pxc + 2 * 32);

    // 2. read previous step's wave partials (latency hidden under comp below)
    const float4 q0 = *(const float4*)&red[pb][0][0];
    const float4 q1 = *(const float4*)&red[pb][2][0];

    // 3. comp from released(h_prev, alpha) — independent of d
    const float xa[4]  = {xv.x, xv.y, xv.z, xv.w};
    const float dta[4] = {dtv.x, dtv.y, dtv.z, dtv.w};
    float alpha[4];
    float w_r = 0.f, w_i = 0.f;
#pragma unroll
    for (int e = 0; e < 4; ++e) {
      alpha[e] = __expf(-dta[e] * a_s);
      const float om    = 1.0f - alpha[e];
      const float rel_r = h_r[e] * om, rel_i = h_i[e] * om;
      const float m2 = fmaf(rel_r, rel_r, fmaf(rel_i, rel_i, 1e-8f));
      const float cm = exp2f(log2f(m2) * (1.0f / 3.0f));     // mag^(2/3)
      const float rr = rel_r + 1e-10f;
      const float invr = __builtin_amdgcn_rsqf(fmaf(rr, rr, fmaf(rel_i, rel_i, 1e-38f)));
      float c_r = cm * rr * invr;    c_r = fminf(fmaxf(c_r, -10.f), 10.f);
      float c_i = cm * rel_i * invr; c_i = fminf(fmaxf(c_i, -10.f), 10.f);
      w_r += c_r; w_i += c_i;
    }
    // wave sum via DPP (full-rate VALU); lane 63 holds the total
    w_r = wave64_sum_l63(w_r);
    w_i = wave64_sum_l63(w_i);
    if (lane == 63) *(float2*)&red[cb][wid][0] = make_float2(w_r, w_i);

    // 4. d update from PREVIOUS step's comp mean (q0/q1); clip to |d|<=20
    const float avg_r = (q0.x + q0.z + q1.x + q1.z) * (1.0f / 1024.0f);
    const float avg_i = (q0.y + q0.w + q1.y + q1.w) * (1.0f / 1024.0f);
    d_r = fmaf(0.01f, avg_r, d_r);
    d_i = fmaf(0.01f, avg_i, d_i);
    const float dm2c = fmaf(d_r, d_r, fmaf(d_i, d_i, 1e-8f));
    if (dm2c > 400.f) { const float sc = 20.f * __builtin_amdgcn_rsqf(dm2c); d_r *= sc; d_i *= sc; }

    // 5. surfaced from d (== reference d_prev for this step) + x_complex
    const float xr2 = xcv.x + 1e-10f;
    const float irx = __builtin_amdgcn_rsqf(fmaf(xr2, xr2, fmaf(xcv.y, xcv.y, 1e-38f)));
    const float dr2 = d_r + 1e-10f;
    const float ird = __builtin_amdgcn_rsqf(fmaf(dr2, dr2, fmaf(d_i, d_i, 1e-38f)));
    const float cosdp = fmaf(xr2, dr2, xcv.y * d_i) * irx * ird;
    const float Tg  = 0.5f * (1.0f + cosdp);                  // cos^2((phix-phid)/2)
    const float md2  = fmaf(d_r, d_r, fmaf(d_i, d_i, 1e-8f));
    const float irm  = __builtin_amdgcn_rsqf(md2);
    const float dmag = md2 * irm;                             // sqrt(md2)
    const float cl   = fminf(fmaxf(dmag, 1e-6f), 20.f);
    const float dscale = cl * __builtin_amdgcn_rsqf(cl);      // sqrt(cl)
    const float sfac = dscale * Tg * __builtin_amdgcn_rcpf(dmag + 1e-8f);
    const float s_r = d_r * sfac, s_i = d_i * sfac;

    // 6. h update + y contribution
    float yv[4];
#pragma unroll
    for (int e = 0; e < 4; ++e) {
      const float bx_r = fmaf(Bv.x, xa[e], s_r) * dta[e];
      const float bx_i = fmaf(Bv.y, xa[e], s_i) * dta[e];
      h_r[e] = fmaf(h_r[e], alpha[e], bx_r);
      h_i[e] = fmaf(h_i[e], alpha[e], bx_i);
      yv[e] = fmaf(Cv.x, h_r[e], -(Cv.y * h_i[e]));
    }
    if (PARTIAL) {
      *(float4*)py = make_float4(yv[0], yv[1], yv[2], yv[3]);   // private buffer, no contention
    } else {
#pragma unroll
      for (int e = 0; e < 4; ++e) atomicAdd(py + e, yv[e]);
    }

    // 7. raw barrier: drain LDS ops only; global loads/stores stay in flight
    asm volatile("s_waitcnt lgkmcnt(0)" ::: "memory");
    __builtin_amdgcn_s_barrier();
    asm volatile("" ::: "memory");

    // rotate prefetched rows and buffers, advance pointers
    xv = xvn; dtv = dtvn; Bv = Bvn; Cv = Cvn; xcv = xcvn;
    xvn = xv2; dtvn = dtv2; Bvn = Bv2; Cvn = Cv2; xcvn = xcv2;
    px += 2048; pdt += 1024; pB += 128; pC += 128; pxc += 32; py += 1024;
    pb = cb; cb = (cb == 2) ? 0 : cb + 1;
  }
}

extern "C" void kernel_launch(void* const* d_in, const int* in_sizes, int n_in,
                              void* d_out, int out_size, void* d_ws, size_t ws_size,
                              hipStream_t stream) {
  const float* x     = (const float*)d_in[0];
  const float* W_in  = (const float*)d_in[1];
  const float* W_xp  = (const float*)d_in[2];
  const float* W_dt  = (const float*)d_in[3];
  const float* b_dt  = (const float*)d_in[4];
  const float* W_out = (const float*)d_in[5];
  const float* b_out = (const float*)d_in[6];
  const float* W_res = (const float*)d_in[7];
  const float* A_log = (const float*)d_in[8];
  float* out = (float*)d_out;

  float* ws     = (float*)d_ws;
  float* siluxz = ws;                               // 2048*2048   = 4,194,304 f
  float* xp     = siluxz + (size_t)2048 * 2048;     // 2048*128    =   262,144 f
  float* dtb    = xp     + (size_t)2048 * 128;      // 2048*1024   = 2,097,152 f
  float* xc     = dtb    + (size_t)2048 * 1024;     // 2048*32     =    65,536 f
  float* ybuf   = xc     + (size_t)2048 * 32;       // 2048*1024   = 2,097,152 f
  float* ypart  = ybuf   + (size_t)2048 * 1024;     // 16*2048*1024 = 33,554,432 f (if it fits)

  const size_t need_bytes = ((size_t)8716288 + (size_t)33554432) * 4;  // base + ypart
  const bool use_part = ws_size >= need_bytes;

  // g1: siluxz = silu(x @ W_in.T)   M=2048 N=2048 K=1024
  gemm_wt<EPI_SILU, false><<<dim3(32, 32), 256, 0, stream>>>(
      x, 1024, nullptr, 0, W_in, 1024, nullptr, siluxz, 2048, 2048, 1024);
  // g2: xp = x_in @ W_xproj.T       N=128 K=1024
  gemm_wt<EPI_NONE, false><<<dim3(32, 2), 256, 0, stream>>>(
      siluxz, 2048, nullptr, 0, W_xp, 1024, nullptr, xp, 128, 128, 1024);
  // g3: dt = softplus(xp[:, :64] @ W_dt.T + b_dt)  N=1024 K=64
  gemm_wt<EPI_SPBIAS, false><<<dim3(32, 16), 256, 0, stream>>>(
      xp, 128, nullptr, 0, W_dt, 64, b_dt, dtb, 1024, 1024, 64);
  // g4: xc = x_in @ W_res.T         N=32 K=1024
  gemm_wt<EPI_NONE, false><<<dim3(32, 1), 256, 0, stream>>>(
      siluxz, 2048, nullptr, 0, W_res, 1024, nullptr, xc, 32, 32, 1024);

  if (use_part) {
    // scan writes private partials (plain stores); then fold over s
    scan_kernel<true><<<dim3(64), dim3(256), 0, stream>>>(
        siluxz, xp, dtb, xc, A_log, ypart, 512);
    reduce_y<<<dim3(2048), 256, 0, stream>>>((const float4*)ypart, (float4*)ybuf, 524288);
  } else {
    // fallback: atomic accumulation into pre-zeroed ybuf
    zero_kernel<<<dim3(2048), 256, 0, stream>>>((float4*)ybuf, (2048 * 1024) / 4);
    scan_kernel<false><<<dim3(64), dim3(256), 0, stream>>>(
        siluxz, xp, dtb, xc, A_log, ybuf, 512);
  }

  // g5: out = (y * silu(z)) @ W_out.T + b_out   N=1024 K=1024
  gemm_wt<EPI_BIAS, true><<<dim3(32, 16), 256, 0, stream>>>(
      ybuf, 1024, siluxz + 1024, 2048, W_out, 1024, b_out, out, 1024, 1024, 1024);
}